// Round 3
// baseline (504.423 us; speedup 1.0000x reference)
//
#include <hip/hip_runtime.h>
#include <stdint.h>
#include <stddef.h>

// ---------- types ----------
typedef _Float16 f16_t;
typedef _Float16 f16x8 __attribute__((ext_vector_type(8)));
typedef _Float16 f16x4 __attribute__((ext_vector_type(4)));
typedef float    f32x4 __attribute__((ext_vector_type(4)));

#define AS_G __attribute__((address_space(1)))
#define AS_L __attribute__((address_space(3)))

__device__ __forceinline__ void gload_lds16(const void* g, void* l) {
  // async global->LDS, 16B per lane; HW writes lds_base + lane*16
  __builtin_amdgcn_global_load_lds((const AS_G uint32_t*)g, (AS_L uint32_t*)l, 16, 0, 0);
}

#define LN_EPS 1e-12f

// ---------- cast fp32 -> f16 (vectorized x4) ----------
__global__ __launch_bounds__(256) void cast_f16_kernel(const float* __restrict__ in,
                                                       f16_t* __restrict__ out) {
  int i = blockIdx.x * 256 + threadIdx.x;
  float4 v = ((const float4*)in)[i];
  f16x4 o = {(f16_t)v.x, (f16_t)v.y, (f16_t)v.z, (f16_t)v.w};
  ((f16x4*)out)[i] = o;
}

// ---------- tiled transpose + cast: in [b][R][C] f32 -> out [b][C][R] f16 ----------
__global__ __launch_bounds__(256) void transpose_f16_kernel(const float* __restrict__ in,
                                                            f16_t* __restrict__ out,
                                                            int R, int C) {
  __shared__ float tile[32][33];
  int b = blockIdx.z;
  const float* inb = in + (size_t)b * R * C;
  f16_t* outb = out + (size_t)b * R * C;
  int tx = threadIdx.x, ty = threadIdx.y;  // 32 x 8
  int c0 = blockIdx.x * 32, r0 = blockIdx.y * 32;
#pragma unroll
  for (int i = 0; i < 32; i += 8)
    tile[ty + i][tx] = inb[(size_t)(r0 + ty + i) * C + (c0 + tx)];
  __syncthreads();
#pragma unroll
  for (int i = 0; i < 32; i += 8)
    outb[(size_t)(c0 + ty + i) * R + (r0 + tx)] = (f16_t)tile[tx][ty + i];
}

// ---------- bias-prep: wqbk[r]=Wq[r]·bk, wkbq[r]=Wk[r]·bq, c0=bq·bk ----------
__global__ __launch_bounds__(256) void wvec_kernel(const float* __restrict__ Wq,
                                                   const float* __restrict__ bq,
                                                   const float* __restrict__ Wk,
                                                   const float* __restrict__ bk,
                                                   float* __restrict__ wqbk,
                                                   float* __restrict__ wkbq,
                                                   float* __restrict__ c0) {
  __shared__ float red[4];
  int bid = blockIdx.x, tid = threadIdx.x;
  const float* rowp; const float* vecp; float* outp;
  if (bid < 1024)      { rowp = Wq + (size_t)bid * 1024; vecp = bk; outp = wqbk + bid; }
  else if (bid < 2048) { rowp = Wk + (size_t)(bid - 1024) * 1024; vecp = bq; outp = wkbq + (bid - 1024); }
  else                 { rowp = bq; vecp = bk; outp = c0; }
  float4 a = ((const float4*)rowp)[tid];
  float4 b = ((const float4*)vecp)[tid];
  float s = a.x * b.x + a.y * b.y + a.z * b.z + a.w * b.w;
#pragma unroll
  for (int off = 32; off > 0; off >>= 1) s += __shfl_xor(s, off, 64);
  if ((tid & 63) == 0) red[tid >> 6] = s;
  __syncthreads();
  if (tid == 0) *outp = red[0] + red[1] + red[2] + red[3];
}

// ---------- cq[m]=X[m]·wqbk, ck[m]=X[m]·wkbq (one block per row) ----------
__global__ __launch_bounds__(256) void cqck_kernel(const float* __restrict__ X,
                                                   const float* __restrict__ wqbk,
                                                   const float* __restrict__ wkbq,
                                                   float* __restrict__ cq,
                                                   float* __restrict__ ck) {
  __shared__ float r1[4], r2[4];
  int m = blockIdx.x, tid = threadIdx.x;
  float4 x = ((const float4*)(X + (size_t)m * 1024))[tid];
  float4 a = ((const float4*)wqbk)[tid];
  float4 b = ((const float4*)wkbq)[tid];
  float s1 = x.x * a.x + x.y * a.y + x.z * a.z + x.w * a.w;
  float s2 = x.x * b.x + x.y * b.y + x.z * b.z + x.w * b.w;
#pragma unroll
  for (int off = 32; off > 0; off >>= 1) { s1 += __shfl_xor(s1, off, 64); s2 += __shfl_xor(s2, off, 64); }
  if ((tid & 63) == 0) { r1[tid >> 6] = s1; r2[tid >> 6] = s2; }
  __syncthreads();
  if (tid == 0) {
    cq[m] = r1[0] + r1[1] + r1[2] + r1[3];
    ck[m] = r2[0] + r2[1] + r2[2] + r2[3];
  }
}

// ---------- 128x128 MFMA GEMM, C = A[MxK]*Bt[NxK]^T, pipelined dbuf K-loop ----------
// BK=32, LDS dbuf 2x(8KB+8KB)=32KB; raw s_barrier + explicit vmcnt(4) keeps the
// next tile's global_load_lds in flight across the barrier (no vmcnt(0) drain).
// Swizzle: chunk c of row r stored at slot c^((r>>1)&3) (row stride 64B) ->
// frag ds_read_b128 at worst 2-way (free); staging lane mapping permuted to match.
// mode 0: plain f16 store          (Wkq, T)
// mode 1: p=exp((acc+cq[row]+ck[col]+c0)*scale) masked, + row-sum partials->lpart
// mode 2: acc*invl[row] -> f16     (PV context)
__global__ __launch_bounds__(256) void gemm_bt_kernel(
    const f16_t* __restrict__ A, const f16_t* __restrict__ Bt, f16_t* __restrict__ C,
    const float* __restrict__ cq, const float* __restrict__ ck, const float* __restrict__ c0p,
    const int* __restrict__ mask, const float* __restrict__ invl, float* __restrict__ lpart,
    int lda, int ldb, int ldc, int K, float scale, int mode,
    size_t sA, size_t sB, size_t sC) {
  __shared__ f16_t As[2][128 * 32];
  __shared__ f16_t Bs[2][128 * 32];

  const int tid = threadIdx.x;
  const int lane = tid & 63;
  const int wv = tid >> 6;          // wave 0..3
  const int m16 = lane & 15;
  const int quad = lane >> 4;
  const int wr = (wv >> 1) * 64;    // wave row offset
  const int wc = (wv & 1) * 64;     // wave col offset

  const f16_t* Ab = A + blockIdx.z * sA + (size_t)blockIdx.x * 128 * lda;
  const f16_t* Bb = Bt + blockIdx.z * sB + (size_t)blockIdx.y * 128 * ldb;

  // staging: wave wv fills tile rows [wv*32, wv*32+32) of A and B, 2 calls each.
  // call lane -> row_local = lane>>2 (16 rows), slot = lane&3;
  // global chunk = slot ^ ((row>>1)&3) = (lane&3) ^ ((lane>>3)&3)
  const int ch = ((lane & 3) ^ ((lane >> 3) & 3)) * 8;
  const int r0 = wv * 32 + (lane >> 2);
  const f16_t* gA0 = Ab + (size_t)r0 * lda + ch;
  const f16_t* gA1 = Ab + (size_t)(r0 + 16) * lda + ch;
  const f16_t* gB0 = Bb + (size_t)r0 * ldb + ch;
  const f16_t* gB1 = Bb + (size_t)(r0 + 16) * ldb + ch;
  const int ldsA0 = (wv * 32) * 32, ldsA1 = (wv * 32 + 16) * 32;

  // fragment read offsets: row=(wr|wc)+t*16+m16, chunk=quad,
  // slot = quad ^ ((m16>>1)&3); addr(elem) = row*32 + slot*8
  const int aslot = (quad ^ ((m16 >> 1) & 3)) * 8;
  int aoff[4], boff[4];
#pragma unroll
  for (int t = 0; t < 4; ++t) {
    aoff[t] = (wr + t * 16 + m16) * 32 + aslot;
    boff[t] = (wc + t * 16 + m16) * 32 + aslot;
  }

  f32x4 acc[4][4] = {};
  const int nk = K >> 5;

  // prologue: fill buf0
  gload_lds16(gA0, &As[0][ldsA0]);
  gload_lds16(gA1, &As[0][ldsA1]);
  gload_lds16(gB0, &Bs[0][ldsA0]);
  gload_lds16(gB1, &Bs[0][ldsA1]);

  int buf = 0;
  for (int it = 0; it < nk; ++it) {
    if (it + 1 < nk) {
      const int k0 = (it + 1) << 5;
      gload_lds16(gA0 + k0, &As[buf ^ 1][ldsA0]);
      gload_lds16(gA1 + k0, &As[buf ^ 1][ldsA1]);
      gload_lds16(gB0 + k0, &Bs[buf ^ 1][ldsA0]);
      gload_lds16(gB1 + k0, &Bs[buf ^ 1][ldsA1]);
      asm volatile("s_waitcnt vmcnt(4)" ::: "memory");   // own cur-buf loads done
    } else {
      asm volatile("s_waitcnt vmcnt(0)" ::: "memory");
    }
    asm volatile("s_barrier" ::: "memory");              // no vmcnt(0) drain

    f16x8 af[4], bfr[4];
#pragma unroll
    for (int t = 0; t < 4; ++t) {
      af[t]  = *(const f16x8*)&As[buf][aoff[t]];
      bfr[t] = *(const f16x8*)&Bs[buf][boff[t]];
    }
#pragma unroll
    for (int rt = 0; rt < 4; ++rt)
#pragma unroll
      for (int ct = 0; ct < 4; ++ct)
        acc[rt][ct] = __builtin_amdgcn_mfma_f32_16x16x32_f16(af[rt], bfr[ct], acc[rt][ct], 0, 0, 0);

    asm volatile("s_barrier" ::: "memory");              // compute done before next overwrite
    buf ^= 1;
  }

  // epilogue; C/D layout: col = lane&15, row = quad*4 + reg  [m89-verified]
  f16_t* Cb = C + blockIdx.z * sC;
  const int row0 = blockIdx.x * 128 + wr + quad * 4;
  const int col0 = blockIdx.y * 128 + wc + m16;
  if (mode == 0) {
#pragma unroll
    for (int ct = 0; ct < 4; ++ct)
#pragma unroll
      for (int rt = 0; rt < 4; ++rt)
#pragma unroll
        for (int r = 0; r < 4; ++r)
          Cb[(size_t)(row0 + rt * 16 + r) * ldc + col0 + ct * 16] = (f16_t)acc[rt][ct][r];
  } else if (mode == 1) {
    const int* mp = mask + blockIdx.z * 2048;
    const size_t rowg0 = blockIdx.z * 2048 + row0;
    const float c0 = *c0p;
    float rsum[4][4];
#pragma unroll
    for (int rt = 0; rt < 4; ++rt)
#pragma unroll
      for (int r = 0; r < 4; ++r) rsum[rt][r] = 0.f;
#pragma unroll
    for (int ct = 0; ct < 4; ++ct) {
      int col = col0 + ct * 16;
      bool keep = (mp[col] != 0);
      float ckv = ck[blockIdx.z * 2048 + col];
#pragma unroll
      for (int rt = 0; rt < 4; ++rt)
#pragma unroll
        for (int r = 0; r < 4; ++r) {
          float cqv = cq[rowg0 + rt * 16 + r];
          float p = keep ? __expf((acc[rt][ct][r] + cqv + ckv + c0) * scale) : 0.f;
          rsum[rt][r] += p;
          Cb[(size_t)(row0 + rt * 16 + r) * ldc + col] = (f16_t)p;
        }
    }
    // reduce row sums across the 16 m16-lanes of each quad, write partials
    const int chunk = blockIdx.y * 2 + (wv & 1);
#pragma unroll
    for (int rt = 0; rt < 4; ++rt)
#pragma unroll
      for (int r = 0; r < 4; ++r) {
        float v = rsum[rt][r];
        v += __shfl_xor(v, 1, 16);
        v += __shfl_xor(v, 2, 16);
        v += __shfl_xor(v, 4, 16);
        v += __shfl_xor(v, 8, 16);
        if (m16 == 0) lpart[(rowg0 + rt * 16 + r) * 32 + chunk] = v;
      }
  } else {
    const size_t rowg0 = blockIdx.z * 2048 + row0;
#pragma unroll
    for (int rt = 0; rt < 4; ++rt)
#pragma unroll
      for (int r = 0; r < 4; ++r) {
        float il = invl[rowg0 + rt * 16 + r];
#pragma unroll
        for (int ct = 0; ct < 4; ++ct)
          Cb[(size_t)(row0 + rt * 16 + r) * ldc + col0 + ct * 16] = (f16_t)(acc[rt][ct][r] * il);
      }
  }
}

// ---------- l reduce: invl[m] = 1 / sum(lpart[m][0..32)) ----------
__global__ __launch_bounds__(256) void lreduce_kernel(const float* __restrict__ lpart,
                                                      float* __restrict__ invl) {
  int m = blockIdx.x * 256 + threadIdx.x;
  const float4* p = (const float4*)(lpart + (size_t)m * 32);
  float s = 0.f;
#pragma unroll
  for (int j = 0; j < 8; ++j) {
    float4 v = p[j];
    s += v.x + v.y + v.z + v.w;
  }
  invl[m] = 1.0f / fmaxf(s, 1e-30f);
}

// ---------- residual + LayerNorm: out[row] = LN(X[row] + Ctx[row]) ----------
__global__ __launch_bounds__(256) void ln_kernel(const float* __restrict__ X,
                                                 const f16_t* __restrict__ Ctx,
                                                 const float* __restrict__ gamma,
                                                 const float* __restrict__ beta,
                                                 float* __restrict__ out) {
  __shared__ float r1[4], r2[4];
  const int tid = threadIdx.x;
  const size_t base = (size_t)blockIdx.x * 1024;
  float4 xv = ((const float4*)(X + base))[tid];
  f16x4 cv = ((const f16x4*)(Ctx + base))[tid];
  float v0 = xv.x + (float)cv[0];
  float v1 = xv.y + (float)cv[1];
  float v2 = xv.z + (float)cv[2];
  float v3 = xv.w + (float)cv[3];
  float s1 = v0 + v1 + v2 + v3;
  float s2 = v0 * v0 + v1 * v1 + v2 * v2 + v3 * v3;
#pragma unroll
  for (int off = 32; off > 0; off >>= 1) {
    s1 += __shfl_xor(s1, off, 64);
    s2 += __shfl_xor(s2, off, 64);
  }
  if ((tid & 63) == 0) { r1[tid >> 6] = s1; r2[tid >> 6] = s2; }
  __syncthreads();
  s1 = r1[0] + r1[1] + r1[2] + r1[3];
  s2 = r2[0] + r2[1] + r2[2] + r2[3];
  float mu = s1 * (1.0f / 1024.0f);
  float var = s2 * (1.0f / 1024.0f) - mu * mu;
  float rs = rsqrtf(fmaxf(var, 0.0f) + LN_EPS);
  float4 gv = ((const float4*)gamma)[tid];
  float4 bv = ((const float4*)beta)[tid];
  float4 o;
  o.x = (v0 - mu) * rs * gv.x + bv.x;
  o.y = (v1 - mu) * rs * gv.y + bv.y;
  o.z = (v2 - mu) * rs * gv.z + bv.z;
  o.w = (v3 - mu) * rs * gv.w + bv.w;
  ((float4*)(out + base))[tid] = o;
}

// ---------- launch ----------
extern "C" void kernel_launch(void* const* d_in, const int* in_sizes, int n_in,
                              void* d_out, int out_size, void* d_ws, size_t ws_size,
                              hipStream_t stream) {
  const float* X     = (const float*)d_in[0];  // [8,2048,1024]
  const int*   masks = (const int*)d_in[1];    // [8,2048]
  const float* Wq    = (const float*)d_in[2];  // [1024,1024]
  const float* bq    = (const float*)d_in[3];
  const float* Wk    = (const float*)d_in[4];
  const float* bk    = (const float*)d_in[5];
  const float* gamma = (const float*)d_in[6];
  const float* beta  = (const float*)d_in[7];
  float* out = (float*)d_out;

  if (ws_size < 115343360u) return;  // need ~110 MiB
  char* ws = (char*)d_ws;
  f16_t* Xb   = (f16_t*)(ws + 0);           // [16384][1024] f16 (later Ctx)
  f16_t* Xt   = (f16_t*)(ws + 33554432);    // [8][1024][2048] f16
  f16_t* T    = (f16_t*)(ws + 67108864);    // [16384][1024] f16
  f16_t* Wqf  = (f16_t*)(ws + 100663296);   // [1024][1024] f16
  f16_t* Wkf  = (f16_t*)(ws + 102760448);   // [1024][1024] f16
  f16_t* Wkq  = (f16_t*)(ws + 104857600);   // [1024][1024] f16 (Wk·Wq^T)
  float* lpart= (float*)(ws + 106954752);   // [16384][32] f32
  float* cq   = (float*)(ws + 109051904);   // [16384]
  float* ck   = (float*)(ws + 109117440);   // [16384]
  float* invl = (float*)(ws + 109182976);   // [16384]
  float* wqbk = (float*)(ws + 109248512);   // [1024]
  float* wkbq = (float*)(ws + 109252608);   // [1024]
  float* c0   = (float*)(ws + 109256704);   // [1]
  f16_t* Ctx  = Xb;
  f16_t* probs = (f16_t*)d_out;             // [8][2048][2048] f16 == 64 MiB

  const size_t SH = 2048u * 1024u;
  const size_t SS = 2048u * 2048u;
  const size_t HS = 1024u * 2048u;

  // 1. casts / transpose / bias vectors
  cast_f16_kernel<<<16384, 256, 0, stream>>>(X, Xb);
  cast_f16_kernel<<<1024, 256, 0, stream>>>(Wq, Wqf);
  cast_f16_kernel<<<1024, 256, 0, stream>>>(Wk, Wkf);
  transpose_f16_kernel<<<dim3(32, 64, 8), dim3(32, 8), 0, stream>>>(X, Xt, 2048, 1024);
  wvec_kernel<<<2049, 256, 0, stream>>>(Wq, bq, Wk, bk, wqbk, wkbq, c0);
  cqck_kernel<<<16384, 256, 0, stream>>>(X, wqbk, wkbq, cq, ck);

  // 2. Wkq = Wk · Wq^T   (so T = Xb · Wkq^T = X·Wq·Wk^T)
  gemm_bt_kernel<<<dim3(8, 8, 1), 256, 0, stream>>>(
      Wkf, Wqf, Wkq, nullptr, nullptr, nullptr, nullptr, nullptr, nullptr,
      1024, 1024, 1024, 1024, 0.f, 0, 0, 0, 0);

  // 3. T = Xb · Wkq^T   (M=16384, N=1024, K=1024)
  gemm_bt_kernel<<<dim3(128, 8, 1), 256, 0, stream>>>(
      Xb, Wkq, T, nullptr, nullptr, nullptr, nullptr, nullptr, nullptr,
      1024, 1024, 1024, 1024, 0.f, 0, 0, 0, 0);

  // 4. p = exp((T·X^T + bias-terms)/32) masked, + row-sum partials
  gemm_bt_kernel<<<dim3(16, 16, 8), 256, 0, stream>>>(
      T, Xb, probs, cq, ck, c0, masks, nullptr, lpart,
      1024, 1024, 2048, 1024, 0.03125f, 1, SH, SH, SS);

  // 5. invl = 1/rowsum
  lreduce_kernel<<<64, 256, 0, stream>>>(lpart, invl);

  // 6. context = (p/l) @ X   (per batch: M=2048, N=1024, K=2048)
  gemm_bt_kernel<<<dim3(16, 8, 8), 256, 0, stream>>>(
      probs, Xt, Ctx, nullptr, nullptr, nullptr, nullptr, invl, nullptr,
      2048, 2048, 1024, 2048, 0.f, 2, SS, HS, SH);

  // 7. out = LayerNorm(X + context)
  ln_kernel<<<16384, 256, 0, stream>>>(X, Ctx, gamma, beta, out);
}

// Round 4
// 479.246 us; speedup vs baseline: 1.0525x; 1.0525x over previous
//
#include <hip/hip_runtime.h>
#include <stdint.h>
#include <stddef.h>

// ---------- types ----------
typedef _Float16 f16_t;
typedef _Float16 f16x8 __attribute__((ext_vector_type(8)));
typedef _Float16 f16x4 __attribute__((ext_vector_type(4)));
typedef float    f32x4 __attribute__((ext_vector_type(4)));

#define AS_G __attribute__((address_space(1)))
#define AS_L __attribute__((address_space(3)))

__device__ __forceinline__ void gload_lds16(const void* g, void* l) {
  // async global->LDS, 16B per lane; HW writes lds_base + lane*16
  __builtin_amdgcn_global_load_lds((const AS_G uint32_t*)g, (AS_L uint32_t*)l, 16, 0, 0);
}

#define LN_EPS 1e-12f

// ---------- cast fp32 -> f16 (vectorized x4) ----------
__global__ __launch_bounds__(256) void cast_f16_kernel(const float* __restrict__ in,
                                                       f16_t* __restrict__ out) {
  int i = blockIdx.x * 256 + threadIdx.x;
  float4 v = ((const float4*)in)[i];
  f16x4 o = {(f16_t)v.x, (f16_t)v.y, (f16_t)v.z, (f16_t)v.w};
  ((f16x4*)out)[i] = o;
}

// ---------- fused X prep: Xb = f16(X) row-major, Xt = f16(X)^T per batch ----------
__global__ __launch_bounds__(256) void xprep_kernel(const float* __restrict__ in,
                                                    f16_t* __restrict__ xb,
                                                    f16_t* __restrict__ xt) {
  __shared__ float tile[32][33];
  int b = blockIdx.z;
  const float* inb = in + (size_t)b * 2048 * 1024;
  f16_t* xbb = xb + (size_t)b * 2048 * 1024;
  f16_t* xtb = xt + (size_t)b * 1024 * 2048;
  int tx = threadIdx.x, ty = threadIdx.y;  // 32 x 8
  int c0 = blockIdx.x * 32, r0 = blockIdx.y * 32;
#pragma unroll
  for (int i = 0; i < 32; i += 8) {
    float v = inb[(size_t)(r0 + ty + i) * 1024 + (c0 + tx)];
    tile[ty + i][tx] = v;
    xbb[(size_t)(r0 + ty + i) * 1024 + (c0 + tx)] = (f16_t)v;
  }
  __syncthreads();
#pragma unroll
  for (int i = 0; i < 32; i += 8)
    xtb[(size_t)(c0 + ty + i) * 2048 + (r0 + tx)] = (f16_t)tile[tx][ty + i];
}

// ---------- bias-prep: wqbk[r]=Wq[r]·bk, wkbq[r]=Wk[r]·bq, c0=bq·bk ----------
__global__ __launch_bounds__(256) void wvec_kernel(const float* __restrict__ Wq,
                                                   const float* __restrict__ bq,
                                                   const float* __restrict__ Wk,
                                                   const float* __restrict__ bk,
                                                   float* __restrict__ wqbk,
                                                   float* __restrict__ wkbq,
                                                   float* __restrict__ c0) {
  __shared__ float red[4];
  int bid = blockIdx.x, tid = threadIdx.x;
  const float* rowp; const float* vecp; float* outp;
  if (bid < 1024)      { rowp = Wq + (size_t)bid * 1024; vecp = bk; outp = wqbk + bid; }
  else if (bid < 2048) { rowp = Wk + (size_t)(bid - 1024) * 1024; vecp = bq; outp = wkbq + (bid - 1024); }
  else                 { rowp = bq; vecp = bk; outp = c0; }
  float4 a = ((const float4*)rowp)[tid];
  float4 b = ((const float4*)vecp)[tid];
  float s = a.x * b.x + a.y * b.y + a.z * b.z + a.w * b.w;
#pragma unroll
  for (int off = 32; off > 0; off >>= 1) s += __shfl_xor(s, off, 64);
  if ((tid & 63) == 0) red[tid >> 6] = s;
  __syncthreads();
  if (tid == 0) *outp = red[0] + red[1] + red[2] + red[3];
}

// ---------- cq[m]=X[m]·wqbk, ck[m]=X[m]·wkbq (one block per row) ----------
__global__ __launch_bounds__(256) void cqck_kernel(const float* __restrict__ X,
                                                   const float* __restrict__ wqbk,
                                                   const float* __restrict__ wkbq,
                                                   float* __restrict__ cq,
                                                   float* __restrict__ ck) {
  __shared__ float r1[4], r2[4];
  int m = blockIdx.x, tid = threadIdx.x;
  float4 x = ((const float4*)(X + (size_t)m * 1024))[tid];
  float4 a = ((const float4*)wqbk)[tid];
  float4 b = ((const float4*)wkbq)[tid];
  float s1 = x.x * a.x + x.y * a.y + x.z * a.z + x.w * a.w;
  float s2 = x.x * b.x + x.y * b.y + x.z * b.z + x.w * b.w;
#pragma unroll
  for (int off = 32; off > 0; off >>= 1) { s1 += __shfl_xor(s1, off, 64); s2 += __shfl_xor(s2, off, 64); }
  if ((tid & 63) == 0) { r1[tid >> 6] = s1; r2[tid >> 6] = s2; }
  __syncthreads();
  if (tid == 0) {
    cq[m] = r1[0] + r1[1] + r1[2] + r1[3];
    ck[m] = r2[0] + r2[1] + r2[2] + r2[3];
  }
}

// ---------- 128x128 MFMA GEMM, C = A[MxK]*Bt[NxK]^T — R2-proven K-loop ----------
// BK=64, single-buffered 32KB LDS, XOR swizzle (chunk c of row r at slot c^(r&7))
// -> SQ_LDS_BANK_CONFLICT == 0 measured. Two __syncthreads per K-iter (compiler
// manages waitcnt; hand-rolled vmcnt pipelines regressed — R3 post-mortem).
// mode 0: plain f16 store          (Wkq, T)
// mode 1: p=exp((acc+cq[row]+ck[col]+c0)*scale) masked, + row-sum partials->lpart
// mode 2: acc*invl[row] -> f16     (PV context)
__global__ __launch_bounds__(256) void gemm_bt_kernel(
    const f16_t* __restrict__ A, const f16_t* __restrict__ Bt, f16_t* __restrict__ C,
    const float* __restrict__ cq, const float* __restrict__ ck, const float* __restrict__ c0p,
    const int* __restrict__ mask, const float* __restrict__ invl, float* __restrict__ lpart,
    int lda, int ldb, int ldc, int K, float scale, int mode,
    size_t sA, size_t sB, size_t sC) {
  __shared__ f16_t As[128 * 64];
  __shared__ f16_t Bs[128 * 64];

  const int tid = threadIdx.x;
  const int lane = tid & 63;
  const int wv = tid >> 6;          // wave 0..3
  const int m16 = lane & 15;
  const int quad = lane >> 4;
  const int wr = (wv >> 1) * 64;    // wave row offset in tile
  const int wc = (wv & 1) * 64;     // wave col offset in tile

  const f16_t* Ab = A + blockIdx.z * sA + (size_t)blockIdx.x * 128 * lda;
  const f16_t* Bb = Bt + blockIdx.z * sB + (size_t)blockIdx.y * 128 * ldb;

  // staging: each wave stages 32 rows of A and B per iter, 4 calls of 1KB each.
  // call j covers rows wv*32 + j*8 + (0..7); lane = row_local8*8 + slot;
  // content chunk = slot ^ (row&7)  (the XOR swizzle).
  const int lr8 = lane >> 3;            // 0..7
  const int ch8 = (lane & 7) ^ lr8;     // swizzled chunk this lane fetches
  const f16_t* gA[4]; const f16_t* gB[4];
  f16_t* lA[4]; f16_t* lB[4];
#pragma unroll
  for (int j = 0; j < 4; ++j) {
    int row = wv * 32 + j * 8 + lr8;
    gA[j] = Ab + (size_t)row * lda + ch8 * 8;
    gB[j] = Bb + (size_t)row * ldb + ch8 * 8;
    lA[j] = &As[(wv * 32 + j * 8) * 64];
    lB[j] = &Bs[(wv * 32 + j * 8) * 64];
  }

  // fragment-read offsets (elements): row r, chunk c -> r*64 + (c^(r&7))*8
  int aoff[4], boff[4], swz[2];
#pragma unroll
  for (int t = 0; t < 4; ++t) {
    aoff[t] = (wr + t * 16 + m16) * 64;
    boff[t] = (wc + t * 16 + m16) * 64;
  }
#pragma unroll
  for (int s = 0; s < 2; ++s)
    swz[s] = (((s << 2) | quad) ^ (m16 & 7)) * 8;

  f32x4 acc[4][4] = {};

  for (int k0 = 0; k0 < K; k0 += 64) {
#pragma unroll
    for (int j = 0; j < 4; ++j) {
      gload_lds16(gA[j] + k0, lA[j]);
      gload_lds16(gB[j] + k0, lB[j]);
    }
    __syncthreads();  // drains vmcnt, publishes LDS

#pragma unroll
    for (int s = 0; s < 2; ++s) {
      f16x8 af[4], bfr[4];
#pragma unroll
      for (int t = 0; t < 4; ++t) {
        af[t]  = *(const f16x8*)&As[aoff[t] + swz[s]];
        bfr[t] = *(const f16x8*)&Bs[boff[t] + swz[s]];
      }
#pragma unroll
      for (int rt = 0; rt < 4; ++rt)
#pragma unroll
        for (int ct = 0; ct < 4; ++ct)
          acc[rt][ct] = __builtin_amdgcn_mfma_f32_16x16x32_f16(af[rt], bfr[ct], acc[rt][ct], 0, 0, 0);
    }
    __syncthreads();
  }

  // epilogue; C/D layout: col = lane&15, row = quad*4 + reg  [m89-verified]
  f16_t* Cb = C + blockIdx.z * sC;
  const int row0 = blockIdx.x * 128 + wr + quad * 4;
  const int col0 = blockIdx.y * 128 + wc + m16;
  if (mode == 0) {
#pragma unroll
    for (int ct = 0; ct < 4; ++ct)
#pragma unroll
      for (int rt = 0; rt < 4; ++rt)
#pragma unroll
        for (int r = 0; r < 4; ++r)
          Cb[(size_t)(row0 + rt * 16 + r) * ldc + col0 + ct * 16] = (f16_t)acc[rt][ct][r];
  } else if (mode == 1) {
    const int* mp = mask + blockIdx.z * 2048;
    const size_t rowg0 = blockIdx.z * 2048 + row0;
    const float c0 = *c0p;
    float rsum[4][4];
#pragma unroll
    for (int rt = 0; rt < 4; ++rt)
#pragma unroll
      for (int r = 0; r < 4; ++r) rsum[rt][r] = 0.f;
#pragma unroll
    for (int ct = 0; ct < 4; ++ct) {
      int col = col0 + ct * 16;
      bool keep = (mp[col] != 0);
      float ckv = ck[blockIdx.z * 2048 + col];
#pragma unroll
      for (int rt = 0; rt < 4; ++rt)
#pragma unroll
        for (int r = 0; r < 4; ++r) {
          float cqv = cq[rowg0 + rt * 16 + r];
          float p = keep ? __expf((acc[rt][ct][r] + cqv + ckv + c0) * scale) : 0.f;
          rsum[rt][r] += p;
          Cb[(size_t)(row0 + rt * 16 + r) * ldc + col] = (f16_t)p;
        }
    }
    // reduce row sums across the 16 m16-lanes of each quad, write partials
    const int chunk = blockIdx.y * 2 + (wv & 1);
#pragma unroll
    for (int rt = 0; rt < 4; ++rt)
#pragma unroll
      for (int r = 0; r < 4; ++r) {
        float v = rsum[rt][r];
        v += __shfl_xor(v, 1, 16);
        v += __shfl_xor(v, 2, 16);
        v += __shfl_xor(v, 4, 16);
        v += __shfl_xor(v, 8, 16);
        if (m16 == 0) lpart[(rowg0 + rt * 16 + r) * 32 + chunk] = v;
      }
  } else {
    const size_t rowg0 = blockIdx.z * 2048 + row0;
#pragma unroll
    for (int rt = 0; rt < 4; ++rt)
#pragma unroll
      for (int r = 0; r < 4; ++r) {
        float il = invl[rowg0 + rt * 16 + r];
#pragma unroll
        for (int ct = 0; ct < 4; ++ct)
          Cb[(size_t)(row0 + rt * 16 + r) * ldc + col0 + ct * 16] = (f16_t)(acc[rt][ct][r] * il);
      }
  }
}

// ---------- l reduce: invl[m] = 1 / sum(lpart[m][0..32)) ----------
__global__ __launch_bounds__(256) void lreduce_kernel(const float* __restrict__ lpart,
                                                      float* __restrict__ invl) {
  int m = blockIdx.x * 256 + threadIdx.x;
  const float4* p = (const float4*)(lpart + (size_t)m * 32);
  float s = 0.f;
#pragma unroll
  for (int j = 0; j < 8; ++j) {
    float4 v = p[j];
    s += v.x + v.y + v.z + v.w;
  }
  invl[m] = 1.0f / fmaxf(s, 1e-30f);
}

// ---------- residual + LayerNorm: out[row] = LN(X[row] + Ctx[row]) ----------
__global__ __launch_bounds__(256) void ln_kernel(const float* __restrict__ X,
                                                 const f16_t* __restrict__ Ctx,
                                                 const float* __restrict__ gamma,
                                                 const float* __restrict__ beta,
                                                 float* __restrict__ out) {
  __shared__ float r1[4], r2[4];
  const int tid = threadIdx.x;
  const size_t base = (size_t)blockIdx.x * 1024;
  float4 xv = ((const float4*)(X + base))[tid];
  f16x4 cv = ((const f16x4*)(Ctx + base))[tid];
  float v0 = xv.x + (float)cv[0];
  float v1 = xv.y + (float)cv[1];
  float v2 = xv.z + (float)cv[2];
  float v3 = xv.w + (float)cv[3];
  float s1 = v0 + v1 + v2 + v3;
  float s2 = v0 * v0 + v1 * v1 + v2 * v2 + v3 * v3;
#pragma unroll
  for (int off = 32; off > 0; off >>= 1) {
    s1 += __shfl_xor(s1, off, 64);
    s2 += __shfl_xor(s2, off, 64);
  }
  if ((tid & 63) == 0) { r1[tid >> 6] = s1; r2[tid >> 6] = s2; }
  __syncthreads();
  s1 = r1[0] + r1[1] + r1[2] + r1[3];
  s2 = r2[0] + r2[1] + r2[2] + r2[3];
  float mu = s1 * (1.0f / 1024.0f);
  float var = s2 * (1.0f / 1024.0f) - mu * mu;
  float rs = rsqrtf(fmaxf(var, 0.0f) + LN_EPS);
  float4 gv = ((const float4*)gamma)[tid];
  float4 bv = ((const float4*)beta)[tid];
  float4 o;
  o.x = (v0 - mu) * rs * gv.x + bv.x;
  o.y = (v1 - mu) * rs * gv.y + bv.y;
  o.z = (v2 - mu) * rs * gv.z + bv.z;
  o.w = (v3 - mu) * rs * gv.w + bv.w;
  ((float4*)(out + base))[tid] = o;
}

// ---------- launch ----------
extern "C" void kernel_launch(void* const* d_in, const int* in_sizes, int n_in,
                              void* d_out, int out_size, void* d_ws, size_t ws_size,
                              hipStream_t stream) {
  const float* X     = (const float*)d_in[0];  // [8,2048,1024]
  const int*   masks = (const int*)d_in[1];    // [8,2048]
  const float* Wq    = (const float*)d_in[2];  // [1024,1024]
  const float* bq    = (const float*)d_in[3];
  const float* Wk    = (const float*)d_in[4];
  const float* bk    = (const float*)d_in[5];
  const float* gamma = (const float*)d_in[6];
  const float* beta  = (const float*)d_in[7];
  float* out = (float*)d_out;

  if (ws_size < 115343360u) return;  // need ~110 MiB
  char* ws = (char*)d_ws;
  f16_t* Xb   = (f16_t*)(ws + 0);           // [16384][1024] f16 (later Ctx)
  f16_t* Xt   = (f16_t*)(ws + 33554432);    // [8][1024][2048] f16
  f16_t* T    = (f16_t*)(ws + 67108864);    // [16384][1024] f16
  f16_t* Wqf  = (f16_t*)(ws + 100663296);   // [1024][1024] f16
  f16_t* Wkf  = (f16_t*)(ws + 102760448);   // [1024][1024] f16
  f16_t* Wkq  = (f16_t*)(ws + 104857600);   // [1024][1024] f16 (Wk·Wq^T)
  float* lpart= (float*)(ws + 106954752);   // [16384][32] f32
  float* cq   = (float*)(ws + 109051904);   // [16384]
  float* ck   = (float*)(ws + 109117440);   // [16384]
  float* invl = (float*)(ws + 109182976);   // [16384]
  float* wqbk = (float*)(ws + 109248512);   // [1024]
  float* wkbq = (float*)(ws + 109252608);   // [1024]
  float* c0   = (float*)(ws + 109256704);   // [1]
  f16_t* Ctx  = Xb;
  f16_t* probs = (f16_t*)d_out;             // [8][2048][2048] f16 == 64 MiB

  const size_t SH = 2048u * 1024u;
  const size_t SS = 2048u * 2048u;
  const size_t HS = 1024u * 2048u;

  // 1. prep: fused cast+transpose of X, W casts, bias vectors
  xprep_kernel<<<dim3(32, 64, 8), dim3(32, 8), 0, stream>>>(X, Xb, Xt);
  cast_f16_kernel<<<1024, 256, 0, stream>>>(Wq, Wqf);
  cast_f16_kernel<<<1024, 256, 0, stream>>>(Wk, Wkf);
  wvec_kernel<<<2049, 256, 0, stream>>>(Wq, bq, Wk, bk, wqbk, wkbq, c0);
  cqck_kernel<<<16384, 256, 0, stream>>>(X, wqbk, wkbq, cq, ck);

  // 2. Wkq = Wk · Wq^T   (so T = Xb · Wkq^T = X·Wq·Wk^T)
  gemm_bt_kernel<<<dim3(8, 8, 1), 256, 0, stream>>>(
      Wkf, Wqf, Wkq, nullptr, nullptr, nullptr, nullptr, nullptr, nullptr,
      1024, 1024, 1024, 1024, 0.f, 0, 0, 0, 0);

  // 3. T = Xb · Wkq^T   (M=16384, N=1024, K=1024)
  gemm_bt_kernel<<<dim3(128, 8, 1), 256, 0, stream>>>(
      Xb, Wkq, T, nullptr, nullptr, nullptr, nullptr, nullptr, nullptr,
      1024, 1024, 1024, 1024, 0.f, 0, 0, 0, 0);

  // 4. p = exp((T·X^T + bias-terms)/32) masked, + row-sum partials
  gemm_bt_kernel<<<dim3(16, 16, 8), 256, 0, stream>>>(
      T, Xb, probs, cq, ck, c0, masks, nullptr, lpart,
      1024, 1024, 2048, 1024, 0.03125f, 1, SH, SH, SS);

  // 5. invl = 1/rowsum
  lreduce_kernel<<<64, 256, 0, stream>>>(lpart, invl);

  // 6. context = (p/l) @ X   (per batch: M=2048, N=1024, K=2048)
  gemm_bt_kernel<<<dim3(16, 8, 8), 256, 0, stream>>>(
      probs, Xt, Ctx, nullptr, nullptr, nullptr, nullptr, invl, nullptr,
      2048, 2048, 1024, 2048, 0.f, 2, SS, HS, SH);

  // 7. out = LayerNorm(X + context)
  ln_kernel<<<16384, 256, 0, stream>>>(X, Ctx, gamma, beta, out);
}